// Round 1
// baseline (158.934 us; speedup 1.0000x reference)
//
#include <hip/hip_runtime.h>

#define NCHAN 12
#define NBINS 2200
#define HMIN  (-1200.0f)
#define HMAX  (1000.0f)
#define SLICE_ELEMS 65536      // 256*256, one (batch, channel) slab
#define SPLIT 4                // blocks per slab
#define BLOCK 256

// Kernel 1: out = hist_counts (WRITE, not add — d_out is poisoned 0xAA).
__global__ __launch_bounds__(BLOCK)
void init_out(const float* __restrict__ hist, float* __restrict__ out, int n) {
    int i = blockIdx.x * BLOCK + threadIdx.x;
    if (i < n) out[i] = hist[i];
}

// Kernel 2: per-block private LDS histogram over one slab chunk, then
// global float atomicAdd flush into out[c*NBINS + bin].
__global__ __launch_bounds__(BLOCK)
void hist_kernel(const float* __restrict__ x, float* __restrict__ out) {
    __shared__ unsigned int lh[NBINS];
    for (int i = threadIdx.x; i < NBINS; i += BLOCK) lh[i] = 0u;
    __syncthreads();

    const int slice = blockIdx.x / SPLIT;     // = b*NCHAN + c (layout [B,C,H,W])
    const int sub   = blockIdx.x % SPLIT;
    const int c     = slice % NCHAN;
    const int chunk = SLICE_ELEMS / SPLIT;    // elements per block

    const float4* __restrict__ xp =
        (const float4*)(x + (long long)slice * SLICE_ELEMS + (long long)sub * chunk);
    const float scale = (float)NBINS / (HMAX - HMIN);  // == 1.0f, matches ref exactly

    const int n4 = chunk / 4;
    for (int i = threadIdx.x; i < n4; i += BLOCK) {
        float4 v = xp[i];
        float vals[4] = {v.x, v.y, v.z, v.w};
#pragma unroll
        for (int j = 0; j < 4; ++j) {
            float f = vals[j];
            // torch.histc: ignore out-of-range; x == MAX lands in last bin.
            if (f >= HMIN && f <= HMAX) {
                int idx = (int)floorf((f - HMIN) * scale);
                idx = min(idx, NBINS - 1);
                atomicAdd(&lh[idx], 1u);
            }
        }
    }
    __syncthreads();

    float* __restrict__ outc = out + c * NBINS;
    for (int i = threadIdx.x; i < NBINS; i += BLOCK) {
        unsigned int v = lh[i];
        if (v) atomicAdd(&outc[i], (float)v);  // integer-valued, exact in fp32
    }
}

extern "C" void kernel_launch(void* const* d_in, const int* in_sizes, int n_in,
                              void* d_out, int out_size, void* d_ws, size_t ws_size,
                              hipStream_t stream) {
    const float* x    = (const float*)d_in[0];
    const float* hist = (const float*)d_in[1];
    float* out        = (float*)d_out;

    // 1) out = hist_counts
    int nblk = (out_size + BLOCK - 1) / BLOCK;
    init_out<<<nblk, BLOCK, 0, stream>>>(hist, out, out_size);

    // 2) accumulate batch histogram
    int nslices = in_sizes[0] / SLICE_ELEMS;          // 32*12 = 384
    hist_kernel<<<nslices * SPLIT, BLOCK, 0, stream>>>(x, out);
}

// Round 2
// 149.843 us; speedup vs baseline: 1.0607x; 1.0607x over previous
//
#include <hip/hip_runtime.h>

#define NCHAN 12
#define NBINS 2200
#define HMIN  (-1200.0f)
#define HMAX  (1000.0f)
#define SLICE_ELEMS 65536      // 256*256, one (batch, channel) slab
#define SPLIT 2                // blocks per slab -> 768 blocks, 3/CU
#define BLOCK 256

// Kernel 1: out = hist_counts (WRITE, not add — d_out is poisoned 0xAA).
__global__ __launch_bounds__(BLOCK)
void init_out(const float* __restrict__ hist, float* __restrict__ out, int n) {
    int i = blockIdx.x * BLOCK + threadIdx.x;
    if (i < n) out[i] = hist[i];
}

__device__ __forceinline__ void bin4(const float4& v, unsigned int* lh) {
    float vals[4] = {v.x, v.y, v.z, v.w};
#pragma unroll
    for (int j = 0; j < 4; ++j) {
        float f = vals[j];
        // torch.histc: ignore out-of-range; x == MAX lands in last bin.
        if (f >= HMIN && f <= HMAX) {
            int idx = (int)floorf((f - HMIN) * ((float)NBINS / (HMAX - HMIN)));
            idx = min(idx, NBINS - 1);
            atomicAdd(&lh[idx], 1u);
        }
    }
}

// Kernel 2: per-block private LDS histogram over one slab chunk, then
// global float atomicAdd flush into out[c*NBINS + bin].
__global__ __launch_bounds__(BLOCK)
void hist_kernel(const float* __restrict__ x, float* __restrict__ out) {
    __shared__ unsigned int lh[NBINS];
    for (int i = threadIdx.x; i < NBINS; i += BLOCK) lh[i] = 0u;
    __syncthreads();

    const int slice = blockIdx.x / SPLIT;     // = b*NCHAN + c (layout [B,C,H,W])
    const int sub   = blockIdx.x % SPLIT;
    const int c     = slice % NCHAN;
    const int chunk = SLICE_ELEMS / SPLIT;    // 32768 elements per block

    const float4* __restrict__ xp =
        (const float4*)(x + (long long)slice * SLICE_ELEMS + (long long)sub * chunk);

    // chunk/4 = 8192 float4 = 256 threads * 32; process 4 float4/thread/iter
    // (4 independent loads in flight -> hides HBM latency past the LDS atomics).
    const int n4 = chunk / 4;
    for (int i = threadIdx.x; i < n4; i += BLOCK * 4) {
        float4 a = xp[i];
        float4 b = xp[i + BLOCK];
        float4 cc = xp[i + 2 * BLOCK];
        float4 d = xp[i + 3 * BLOCK];
        bin4(a, lh);
        bin4(b, lh);
        bin4(cc, lh);
        bin4(d, lh);
    }
    __syncthreads();

    float* __restrict__ outc = out + c * NBINS;
    for (int i = threadIdx.x; i < NBINS; i += BLOCK) {
        unsigned int v = lh[i];
        if (v) atomicAdd(&outc[i], (float)v);  // integer-valued, exact in fp32
    }
}

extern "C" void kernel_launch(void* const* d_in, const int* in_sizes, int n_in,
                              void* d_out, int out_size, void* d_ws, size_t ws_size,
                              hipStream_t stream) {
    const float* x    = (const float*)d_in[0];
    const float* hist = (const float*)d_in[1];
    float* out        = (float*)d_out;

    // 1) out = hist_counts
    int nblk = (out_size + BLOCK - 1) / BLOCK;
    init_out<<<nblk, BLOCK, 0, stream>>>(hist, out, out_size);

    // 2) accumulate batch histogram
    int nslices = in_sizes[0] / SLICE_ELEMS;          // 32*12 = 384
    hist_kernel<<<nslices * SPLIT, BLOCK, 0, stream>>>(x, out);
}